// Round 1
// baseline (2153.810 us; speedup 1.0000x reference)
//
#include <hip/hip_runtime.h>
#include <math.h>

// Problem constants
#define NB   256      // batch rows
#define DIN  5000
#define NH1  2048
#define NH2  1024
#define NISO 100000
#define NG   25000

typedef __attribute__((ext_vector_type(8))) short bf16x8;
typedef __attribute__((ext_vector_type(4))) float f32x4;

__device__ __forceinline__ unsigned short f2bf_rn(float f) {
  union { float f; unsigned u; } v; v.f = f;
  unsigned r = v.u + 0x7FFFu + ((v.u >> 16) & 1u);
  return (unsigned short)(r >> 16);
}
__device__ __forceinline__ float bf2f(unsigned short h) {
  union { unsigned u; float f; } v; v.u = ((unsigned)h) << 16;
  return v.f;
}

// ---------------------------------------------------------------------------
// Split-bf16 (3-term) GEMM: ~fp32 accuracy via hi/lo decomposition.
// A [M x K] row-major fp32, B [K x N] row-major fp32.
// C accumulated with atomicAdd (C must be zeroed first; bias added later).
// grid = (N/BN, M/64, nz), block = 256 (4 waves x 16 rows). BM fixed at 64.
// ---------------------------------------------------------------------------
template<int BN>
__global__ __launch_bounds__(256) void gemm_split(
    const float* __restrict__ A, const float* __restrict__ Bg,
    float* __restrict__ C, int M, int N, int K, int KC)
{
  constexpr int BM = 64;
  constexpr int BK = 32;
  constexpr int LDT = BK + 8;       // pad keeps b128 alignment, breaks pow2 stride
  constexpr int CT = BN / 16;
  __shared__ unsigned short Ah[BM][LDT], Al[BM][LDT];
  __shared__ unsigned short Bh[BN][LDT], Bl[BN][LDT];
  const int tid = threadIdx.x;
  const int wave = tid >> 6, lane = tid & 63;
  const int fr = lane & 15, fq = lane >> 4;
  const int n0 = blockIdx.x * BN, m0 = blockIdx.y * BM;
  const int kb0 = blockIdx.z * KC;
  const int ke = min(kb0 + KC, K);
  const int mrow = wave * 16;

  f32x4 acc[CT];
#pragma unroll
  for (int i = 0; i < CT; i++) acc[i] = (f32x4){0.f, 0.f, 0.f, 0.f};

  for (int kb = kb0; kb < ke; kb += BK) {
    // stage A tile (BM x 32) -> hi/lo, layout [m][k]
    for (int s = tid; s < BM * 8; s += 256) {
      int m = s >> 3, kq = (s & 7) * 4;
      int gk = kb + kq;
      const float* ap = A + (size_t)(m0 + m) * K + gk;
      float4 v;
      if (gk + 3 < ke) v = *(const float4*)ap;
      else {
        v.x = (gk     < ke) ? ap[0] : 0.f;
        v.y = (gk + 1 < ke) ? ap[1] : 0.f;
        v.z = (gk + 2 < ke) ? ap[2] : 0.f;
        v.w = (gk + 3 < ke) ? ap[3] : 0.f;
      }
      unsigned short h0 = f2bf_rn(v.x), h1 = f2bf_rn(v.y),
                     h2 = f2bf_rn(v.z), h3 = f2bf_rn(v.w);
      *(ushort4*)&Ah[m][kq] = make_ushort4(h0, h1, h2, h3);
      *(ushort4*)&Al[m][kq] = make_ushort4(f2bf_rn(v.x - bf2f(h0)),
                                           f2bf_rn(v.y - bf2f(h1)),
                                           f2bf_rn(v.z - bf2f(h2)),
                                           f2bf_rn(v.w - bf2f(h3)));
    }
    // stage B tile (32 x BN) transposed to [n][k] -> hi/lo
    for (int s = tid; s < BN * 8; s += 256) {
      int n = s % BN, k0 = (s / BN) * 4;
      unsigned short hh[4], ll[4];
#pragma unroll
      for (int j = 0; j < 4; j++) {
        int gk = kb + k0 + j;
        float v = (gk < ke) ? Bg[(size_t)gk * N + n0 + n] : 0.f;
        hh[j] = f2bf_rn(v);
        ll[j] = f2bf_rn(v - bf2f(hh[j]));
      }
      *(ushort4*)&Bh[n][k0] = make_ushort4(hh[0], hh[1], hh[2], hh[3]);
      *(ushort4*)&Bl[n][k0] = make_ushort4(ll[0], ll[1], ll[2], ll[3]);
    }
    __syncthreads();
    bf16x8 ah = *(const bf16x8*)&Ah[mrow + fr][fq * 8];
    bf16x8 al = *(const bf16x8*)&Al[mrow + fr][fq * 8];
#pragma unroll
    for (int ct = 0; ct < CT; ct++) {
      bf16x8 bh = *(const bf16x8*)&Bh[ct * 16 + fr][fq * 8];
      bf16x8 bl = *(const bf16x8*)&Bl[ct * 16 + fr][fq * 8];
      acc[ct] = __builtin_amdgcn_mfma_f32_16x16x32_bf16(ah, bh, acc[ct], 0, 0, 0);
      acc[ct] = __builtin_amdgcn_mfma_f32_16x16x32_bf16(ah, bl, acc[ct], 0, 0, 0);
      acc[ct] = __builtin_amdgcn_mfma_f32_16x16x32_bf16(al, bh, acc[ct], 0, 0, 0);
    }
    __syncthreads();
  }
  // epilogue: C/D layout col=lane&15, row=(lane>>4)*4+i
#pragma unroll
  for (int ct = 0; ct < CT; ct++) {
    int c = n0 + ct * 16 + fr;
    int r0 = m0 + mrow + fq * 4;
#pragma unroll
    for (int i = 0; i < 4; i++)
      atomicAdd(&C[(size_t)(r0 + i) * N + c], acc[ct][i]);
  }
}

// ---------------------------------------------------------------------------
// GEMM3 (single bf16, memory-bound): h2[256x1024] @ W3[1024x100000] + b3,
// epilogue computes exp(logit) (global row-max shift cancels per-gene; the
// 1e-8 clamp can never bind at these magnitudes), writes E to d_out and
// atomicAdds per-(row,gene) denominators.
// BM=256 (full M: W3 streamed exactly once), BN=80 (100000/80=1250 blocks).
// ---------------------------------------------------------------------------
template<int BN>
__global__ __launch_bounds__(512) void gemm3_exp(
    const float* __restrict__ A,   // h2
    const float* __restrict__ Bg,  // W3
    const float* __restrict__ b3,
    const int* __restrict__ idx,
    float* __restrict__ E,         // d_out, holds exp(logits)
    float* __restrict__ denom)     // [256 x 25000]
{
  constexpr int BM = 256, BK = 32, K = NH2, N = NISO;
  constexpr int LDT = BK + 8;
  constexpr int CT = BN / 16;
  __shared__ unsigned short Ah[BM][LDT];
  __shared__ unsigned short Bh[BN][LDT];
  const int tid = threadIdx.x;
  const int wave = tid >> 6, lane = tid & 63;
  const int fr = lane & 15, fq = lane >> 4;
  const int n0 = blockIdx.x * BN;
  const int mrow = wave * 32;      // 8 waves x 32 rows

  f32x4 acc[2][CT];
#pragma unroll
  for (int r = 0; r < 2; r++)
#pragma unroll
    for (int c = 0; c < CT; c++) acc[r][c] = (f32x4){0.f, 0.f, 0.f, 0.f};

  for (int kb = 0; kb < K; kb += BK) {
    for (int s = tid; s < BM * 8; s += 512) {
      int m = s >> 3, kq = (s & 7) * 4;
      float4 v = *(const float4*)(A + (size_t)m * K + kb + kq);
      *(ushort4*)&Ah[m][kq] =
          make_ushort4(f2bf_rn(v.x), f2bf_rn(v.y), f2bf_rn(v.z), f2bf_rn(v.w));
    }
    for (int s = tid; s < BN * 8; s += 512) {
      int n = s % BN, k0 = (s / BN) * 4;
      unsigned short hh[4];
#pragma unroll
      for (int j = 0; j < 4; j++)
        hh[j] = f2bf_rn(Bg[(size_t)(kb + k0 + j) * N + n0 + n]);
      *(ushort4*)&Bh[n][k0] = make_ushort4(hh[0], hh[1], hh[2], hh[3]);
    }
    __syncthreads();
    bf16x8 a0 = *(const bf16x8*)&Ah[mrow + fr][fq * 8];
    bf16x8 a1 = *(const bf16x8*)&Ah[mrow + 16 + fr][fq * 8];
#pragma unroll
    for (int ct = 0; ct < CT; ct++) {
      bf16x8 b = *(const bf16x8*)&Bh[ct * 16 + fr][fq * 8];
      acc[0][ct] = __builtin_amdgcn_mfma_f32_16x16x32_bf16(a0, b, acc[0][ct], 0, 0, 0);
      acc[1][ct] = __builtin_amdgcn_mfma_f32_16x16x32_bf16(a1, b, acc[1][ct], 0, 0, 0);
    }
    __syncthreads();
  }
#pragma unroll
  for (int ct = 0; ct < CT; ct++) {
    int c = n0 + ct * 16 + fr;
    int g = idx[c];
    float bb = b3[c];
#pragma unroll
    for (int rt = 0; rt < 2; rt++) {
      int r0 = mrow + rt * 16 + fq * 4;
#pragma unroll
      for (int i = 0; i < 4; i++) {
        float e = expf(acc[rt][ct][i] + bb);
        E[(size_t)(r0 + i) * N + c] = e;
        atomicAdd(&denom[(size_t)(r0 + i) * NG + g], e);
      }
    }
  }
}

// ---------------------------------------------------------------------------
// LayerNorm (+bias, biased var, eps=1e-5) + exact GELU. One block per row.
// ---------------------------------------------------------------------------
__global__ __launch_bounds__(256) void ln_gelu(
    const float* __restrict__ hpre, const float* __restrict__ bias,
    const float* __restrict__ gam, const float* __restrict__ beta,
    float* __restrict__ outp, int n)
{
  const int r = blockIdx.x;
  const float* row = hpre + (size_t)r * n;
  float s = 0.f, s2 = 0.f;
  for (int j = threadIdx.x; j < n; j += 256) {
    float v = row[j] + bias[j];
    s += v; s2 += v * v;
  }
#pragma unroll
  for (int o = 32; o > 0; o >>= 1) {
    s  += __shfl_down(s, o);
    s2 += __shfl_down(s2, o);
  }
  __shared__ float red[8];
  const int wave = threadIdx.x >> 6, lane = threadIdx.x & 63;
  if (lane == 0) { red[wave] = s; red[wave + 4] = s2; }
  __syncthreads();
  if (threadIdx.x == 0) {
    float ts = 0.f, t2 = 0.f;
    for (int w = 0; w < 4; w++) { ts += red[w]; t2 += red[w + 4]; }
    float mu = ts / n;
    float var = t2 / n - mu * mu;
    red[0] = mu; red[1] = rsqrtf(var + 1e-5f);
  }
  __syncthreads();
  const float mu = red[0], rs = red[1];
  for (int j = threadIdx.x; j < n; j += 256) {
    float v = (row[j] + bias[j] - mu) * rs * gam[j] + beta[j];
    outp[(size_t)r * n + j] = 0.5f * v * (1.f + erff(v * 0.70710678118654752f));
  }
}

// ---------------------------------------------------------------------------
// Final divide: out[b,i] = E[b,i] / max(denom[b, idx[i]], 1e-8), in-place.
// ---------------------------------------------------------------------------
__global__ __launch_bounds__(256) void div_kernel(
    float* __restrict__ out, const float* __restrict__ denom,
    const int* __restrict__ idx)
{
  const int e = blockIdx.x * 256 + threadIdx.x;       // quad index
  const int row = e / (NISO / 4);
  const int c4 = e % (NISO / 4);
  const int4 g4 = ((const int4*)idx)[c4];
  float4 v = ((const float4*)out)[e];
  const float* dr = denom + (size_t)row * NG;
  v.x /= fmaxf(dr[g4.x], 1e-8f);
  v.y /= fmaxf(dr[g4.y], 1e-8f);
  v.z /= fmaxf(dr[g4.z], 1e-8f);
  v.w /= fmaxf(dr[g4.w], 1e-8f);
  ((float4*)out)[e] = v;
}

// ---------------------------------------------------------------------------
extern "C" void kernel_launch(void* const* d_in, const int* in_sizes, int n_in,
                              void* d_out, int out_size, void* d_ws, size_t ws_size,
                              hipStream_t stream) {
  const float* x   = (const float*)d_in[0];
  const int*   idx = (const int*)  d_in[1];
  const float* W1  = (const float*)d_in[2];
  const float* b1  = (const float*)d_in[3];
  const float* g1  = (const float*)d_in[4];
  const float* be1 = (const float*)d_in[5];
  const float* W2  = (const float*)d_in[6];
  const float* b2  = (const float*)d_in[7];
  const float* g2  = (const float*)d_in[8];
  const float* be2 = (const float*)d_in[9];
  const float* W3  = (const float*)d_in[10];
  const float* b3  = (const float*)d_in[11];
  float* out = (float*)d_out;

  // workspace layout (floats): zeroed region first, then LN outputs
  float* ws      = (float*)d_ws;
  float* h1_pre  = ws;                              // 256*2048
  float* h2_pre  = h1_pre + (size_t)NB * NH1;       // 256*1024
  float* denom   = h2_pre + (size_t)NB * NH2;       // 256*25000
  float* h1      = denom  + (size_t)NB * NG;        // 256*2048
  float* h2      = h1     + (size_t)NB * NH1;       // 256*1024
  const size_t zero_bytes = ((size_t)NB * NH1 + (size_t)NB * NH2 + (size_t)NB * NG) * sizeof(float);
  hipMemsetAsync(d_ws, 0, zero_bytes, stream);

  // layer 1: x @ W1 (split-bf16, K=5000 in 5 chunks of 1000)
  gemm_split<128><<<dim3(NH1 / 128, NB / 64, 5), 256, 0, stream>>>(
      x, W1, h1_pre, NB, NH1, DIN, 1000);
  ln_gelu<<<NB, 256, 0, stream>>>(h1_pre, b1, g1, be1, h1, NH1);

  // layer 2: h1 @ W2 (split-bf16, K=2048 in 4 chunks of 512)
  gemm_split<128><<<dim3(NH2 / 128, NB / 64, 4), 256, 0, stream>>>(
      h1, W2, h2_pre, NB, NH2, NH1, 512);
  ln_gelu<<<NB, 256, 0, stream>>>(h2_pre, b2, g2, be2, h2, NH2);

  // layer 3: h2 @ W3 + b3 -> exp -> E (=d_out) + per-gene denominators
  gemm3_exp<80><<<NISO / 80, 512, 0, stream>>>(h2, W3, b3, idx, out, denom);

  // grouped-softmax normalization, in place on d_out
  div_kernel<<<(NB * NISO / 4) / 256, 256, 0, stream>>>(out, denom, idx);
}

// Round 2
// 1167.757 us; speedup vs baseline: 1.8444x; 1.8444x over previous
//
#include <hip/hip_runtime.h>
#include <math.h>

// Problem constants
#define NB   256      // batch rows
#define DIN  5000
#define NH1  2048
#define NH2  1024
#define NISO 100000
#define NG   25000
#define GH   12500    // genes per LDS half-pass (50 KB)

typedef __attribute__((ext_vector_type(8))) short bf16x8;
typedef __attribute__((ext_vector_type(4))) float f32x4;

__device__ __forceinline__ unsigned short f2bf_rn(float f) {
  union { float f; unsigned u; } v; v.f = f;
  unsigned r = v.u + 0x7FFFu + ((v.u >> 16) & 1u);
  return (unsigned short)(r >> 16);
}
__device__ __forceinline__ float bf2f(unsigned short h) {
  union { unsigned u; float f; } v; v.u = ((unsigned)h) << 16;
  return v.f;
}

// ---------------------------------------------------------------------------
// Split-bf16 (3-term) GEMM: ~fp32 accuracy via hi/lo decomposition.
// A [M x K] row-major fp32, B [K x N] row-major fp32.
// Each blockIdx.z writes its own C slab (no atomics, no zero-init needed);
// the LN kernel sums the slabs.
// grid = (N/BN, M/64, nz), block = 256 (4 waves x 16 rows). BM fixed at 64.
// ---------------------------------------------------------------------------
template<int BN>
__global__ __launch_bounds__(256) void gemm_split(
    const float* __restrict__ A, const float* __restrict__ Bg,
    float* __restrict__ C, int M, int N, int K, int KC)
{
  constexpr int BM = 64;
  constexpr int BK = 32;
  constexpr int LDT = BK + 8;       // pad keeps b128 alignment, breaks pow2 stride
  constexpr int CT = BN / 16;
  __shared__ unsigned short Ah[BM][LDT], Al[BM][LDT];
  __shared__ unsigned short Bh[BN][LDT], Bl[BN][LDT];
  const int tid = threadIdx.x;
  const int wave = tid >> 6, lane = tid & 63;
  const int fr = lane & 15, fq = lane >> 4;
  const int n0 = blockIdx.x * BN, m0 = blockIdx.y * BM;
  const int kb0 = blockIdx.z * KC;
  const int ke = min(kb0 + KC, K);
  const int mrow = wave * 16;
  float* Cz = C + (size_t)blockIdx.z * M * N;

  f32x4 acc[CT];
#pragma unroll
  for (int i = 0; i < CT; i++) acc[i] = (f32x4){0.f, 0.f, 0.f, 0.f};

  for (int kb = kb0; kb < ke; kb += BK) {
    // stage A tile (BM x 32) -> hi/lo, layout [m][k]
    for (int s = tid; s < BM * 8; s += 256) {
      int m = s >> 3, kq = (s & 7) * 4;
      int gk = kb + kq;
      const float* ap = A + (size_t)(m0 + m) * K + gk;
      float4 v;
      if (gk + 3 < ke) v = *(const float4*)ap;
      else {
        v.x = (gk     < ke) ? ap[0] : 0.f;
        v.y = (gk + 1 < ke) ? ap[1] : 0.f;
        v.z = (gk + 2 < ke) ? ap[2] : 0.f;
        v.w = (gk + 3 < ke) ? ap[3] : 0.f;
      }
      unsigned short h0 = f2bf_rn(v.x), h1 = f2bf_rn(v.y),
                     h2 = f2bf_rn(v.z), h3 = f2bf_rn(v.w);
      *(ushort4*)&Ah[m][kq] = make_ushort4(h0, h1, h2, h3);
      *(ushort4*)&Al[m][kq] = make_ushort4(f2bf_rn(v.x - bf2f(h0)),
                                           f2bf_rn(v.y - bf2f(h1)),
                                           f2bf_rn(v.z - bf2f(h2)),
                                           f2bf_rn(v.w - bf2f(h3)));
    }
    // stage B tile (32 x BN) transposed to [n][k] -> hi/lo
    for (int s = tid; s < BN * 8; s += 256) {
      int n = s % BN, k0 = (s / BN) * 4;
      unsigned short hh[4], ll[4];
#pragma unroll
      for (int j = 0; j < 4; j++) {
        int gk = kb + k0 + j;
        float v = (gk < ke) ? Bg[(size_t)gk * N + n0 + n] : 0.f;
        hh[j] = f2bf_rn(v);
        ll[j] = f2bf_rn(v - bf2f(hh[j]));
      }
      *(ushort4*)&Bh[n][k0] = make_ushort4(hh[0], hh[1], hh[2], hh[3]);
      *(ushort4*)&Bl[n][k0] = make_ushort4(ll[0], ll[1], ll[2], ll[3]);
    }
    __syncthreads();
    bf16x8 ah = *(const bf16x8*)&Ah[mrow + fr][fq * 8];
    bf16x8 al = *(const bf16x8*)&Al[mrow + fr][fq * 8];
#pragma unroll
    for (int ct = 0; ct < CT; ct++) {
      bf16x8 bh = *(const bf16x8*)&Bh[ct * 16 + fr][fq * 8];
      bf16x8 bl = *(const bf16x8*)&Bl[ct * 16 + fr][fq * 8];
      acc[ct] = __builtin_amdgcn_mfma_f32_16x16x32_bf16(ah, bh, acc[ct], 0, 0, 0);
      acc[ct] = __builtin_amdgcn_mfma_f32_16x16x32_bf16(ah, bl, acc[ct], 0, 0, 0);
      acc[ct] = __builtin_amdgcn_mfma_f32_16x16x32_bf16(al, bh, acc[ct], 0, 0, 0);
    }
    __syncthreads();
  }
  // epilogue: C/D layout col=lane&15, row=(lane>>4)*4+i ; plain stores
#pragma unroll
  for (int ct = 0; ct < CT; ct++) {
    int c = n0 + ct * 16 + fr;
    int r0 = m0 + mrow + fq * 4;
#pragma unroll
    for (int i = 0; i < 4; i++)
      Cz[(size_t)(r0 + i) * N + c] = acc[ct][i];
  }
}

// ---------------------------------------------------------------------------
// GEMM3 (single bf16, memory-bound): h2[256x1024] @ W3[1024x100000] + b3,
// epilogue writes exp(logit) only (global row-max shift cancels per-gene;
// the 1e-8 clamp can never bind at these magnitudes).
// BM=256 (full M: W3 streamed exactly once), BN=80 (100000/80=1250 blocks).
// ---------------------------------------------------------------------------
template<int BN>
__global__ __launch_bounds__(512) void gemm3_exp(
    const float* __restrict__ A,   // h2
    const float* __restrict__ Bg,  // W3
    const float* __restrict__ b3,
    float* __restrict__ E)         // d_out, holds exp(logits)
{
  constexpr int BM = 256, BK = 32, K = NH2, N = NISO;
  constexpr int LDT = BK + 8;
  constexpr int CT = BN / 16;
  __shared__ unsigned short Ah[BM][LDT];
  __shared__ unsigned short Bh[BN][LDT];
  const int tid = threadIdx.x;
  const int wave = tid >> 6, lane = tid & 63;
  const int fr = lane & 15, fq = lane >> 4;
  const int n0 = blockIdx.x * BN;
  const int mrow = wave * 32;      // 8 waves x 32 rows

  f32x4 acc[2][CT];
#pragma unroll
  for (int r = 0; r < 2; r++)
#pragma unroll
    for (int c = 0; c < CT; c++) acc[r][c] = (f32x4){0.f, 0.f, 0.f, 0.f};

  for (int kb = 0; kb < K; kb += BK) {
    for (int s = tid; s < BM * 8; s += 512) {
      int m = s >> 3, kq = (s & 7) * 4;
      float4 v = *(const float4*)(A + (size_t)m * K + kb + kq);
      *(ushort4*)&Ah[m][kq] =
          make_ushort4(f2bf_rn(v.x), f2bf_rn(v.y), f2bf_rn(v.z), f2bf_rn(v.w));
    }
    for (int s = tid; s < BN * 8; s += 512) {
      int n = s % BN, k0 = (s / BN) * 4;
      unsigned short hh[4];
#pragma unroll
      for (int j = 0; j < 4; j++)
        hh[j] = f2bf_rn(Bg[(size_t)(kb + k0 + j) * N + n0 + n]);
      *(ushort4*)&Bh[n][k0] = make_ushort4(hh[0], hh[1], hh[2], hh[3]);
    }
    __syncthreads();
    bf16x8 a0 = *(const bf16x8*)&Ah[mrow + fr][fq * 8];
    bf16x8 a1 = *(const bf16x8*)&Ah[mrow + 16 + fr][fq * 8];
#pragma unroll
    for (int ct = 0; ct < CT; ct++) {
      bf16x8 b = *(const bf16x8*)&Bh[ct * 16 + fr][fq * 8];
      acc[0][ct] = __builtin_amdgcn_mfma_f32_16x16x32_bf16(a0, b, acc[0][ct], 0, 0, 0);
      acc[1][ct] = __builtin_amdgcn_mfma_f32_16x16x32_bf16(a1, b, acc[1][ct], 0, 0, 0);
    }
    __syncthreads();
  }
#pragma unroll
  for (int ct = 0; ct < CT; ct++) {
    int c = n0 + ct * 16 + fr;
    float bb = b3[c];
#pragma unroll
    for (int rt = 0; rt < 2; rt++) {
      int r0 = mrow + rt * 16 + fq * 4;
#pragma unroll
      for (int i = 0; i < 4; i++)
        E[(size_t)(r0 + i) * N + c] = expf(acc[rt][ct][i] + bb);
    }
  }
}

// ---------------------------------------------------------------------------
// Per-row gene denominators via LDS atomics, two 12500-gene half-passes
// (50 KB LDS). One block per batch row; E row is L2-hot on the second pass.
// ---------------------------------------------------------------------------
__global__ __launch_bounds__(512) void denom_halves(
    const float* __restrict__ E, const int* __restrict__ idx,
    float* __restrict__ denom)
{
  __shared__ float dloc[GH];
  const int r = blockIdx.x;
  const float4* Er = (const float4*)(E + (size_t)r * NISO);
  const int4* I4 = (const int4*)idx;
#pragma unroll
  for (int h = 0; h < 2; h++) {
    const int gbase = h * GH;
    for (int j = threadIdx.x; j < GH; j += 512) dloc[j] = 0.f;
    __syncthreads();
    for (int q = threadIdx.x; q < NISO / 4; q += 512) {
      float4 v = Er[q]; int4 g = I4[q];
      if ((unsigned)(g.x - gbase) < GH) atomicAdd(&dloc[g.x - gbase], v.x);
      if ((unsigned)(g.y - gbase) < GH) atomicAdd(&dloc[g.y - gbase], v.y);
      if ((unsigned)(g.z - gbase) < GH) atomicAdd(&dloc[g.z - gbase], v.z);
      if ((unsigned)(g.w - gbase) < GH) atomicAdd(&dloc[g.w - gbase], v.w);
    }
    __syncthreads();
    for (int j = threadIdx.x; j < GH; j += 512)
      denom[(size_t)r * NG + gbase + j] = dloc[j];
    __syncthreads();
  }
}

// ---------------------------------------------------------------------------
// LayerNorm over summed split-K slabs (+bias, biased var, eps=1e-5) + exact
// GELU. One block (256 thr) per row; per-thread register cache of the summed
// row chunk (n/256 <= 8 elements).
// ---------------------------------------------------------------------------
__global__ __launch_bounds__(256) void ln_gelu_sum(
    const float* __restrict__ slabs, int nslab,
    const float* __restrict__ bias, const float* __restrict__ gam,
    const float* __restrict__ beta, float* __restrict__ outp, int n)
{
  const int r = blockIdx.x;
  float vv[8];
  float s = 0.f, s2 = 0.f;
  int cnt = 0;
  for (int j = threadIdx.x; j < n; j += 256, cnt++) {
    float v = bias[j];
    for (int z = 0; z < nslab; z++)
      v += slabs[((size_t)z * NB + r) * n + j];
    vv[cnt] = v;
    s += v; s2 += v * v;
  }
#pragma unroll
  for (int o = 32; o > 0; o >>= 1) {
    s  += __shfl_down(s, o);
    s2 += __shfl_down(s2, o);
  }
  __shared__ float red[8];
  const int wave = threadIdx.x >> 6, lane = threadIdx.x & 63;
  if (lane == 0) { red[wave] = s; red[wave + 4] = s2; }
  __syncthreads();
  if (threadIdx.x == 0) {
    float ts = 0.f, t2 = 0.f;
    for (int w = 0; w < 4; w++) { ts += red[w]; t2 += red[w + 4]; }
    float mu = ts / n;
    float var = t2 / n - mu * mu;
    red[0] = mu; red[1] = rsqrtf(var + 1e-5f);
  }
  __syncthreads();
  const float mu = red[0], rs = red[1];
  cnt = 0;
  for (int j = threadIdx.x; j < n; j += 256, cnt++) {
    float v = (vv[cnt] - mu) * rs * gam[j] + beta[j];
    outp[(size_t)r * n + j] = 0.5f * v * (1.f + erff(v * 0.70710678118654752f));
  }
}

// ---------------------------------------------------------------------------
// Final divide: out[b,i] = E[b,i] / max(denom[b, idx[i]], 1e-8), in-place.
// ---------------------------------------------------------------------------
__global__ __launch_bounds__(256) void div_kernel(
    float* __restrict__ out, const float* __restrict__ denom,
    const int* __restrict__ idx)
{
  const int e = blockIdx.x * 256 + threadIdx.x;       // quad index
  const int row = e / (NISO / 4);
  const int c4 = e % (NISO / 4);
  const int4 g4 = ((const int4*)idx)[c4];
  float4 v = ((const float4*)out)[e];
  const float* dr = denom + (size_t)row * NG;
  v.x /= fmaxf(dr[g4.x], 1e-8f);
  v.y /= fmaxf(dr[g4.y], 1e-8f);
  v.z /= fmaxf(dr[g4.z], 1e-8f);
  v.w /= fmaxf(dr[g4.w], 1e-8f);
  ((float4*)out)[e] = v;
}

// ---------------------------------------------------------------------------
extern "C" void kernel_launch(void* const* d_in, const int* in_sizes, int n_in,
                              void* d_out, int out_size, void* d_ws, size_t ws_size,
                              hipStream_t stream) {
  const float* x   = (const float*)d_in[0];
  const int*   idx = (const int*)  d_in[1];
  const float* W1  = (const float*)d_in[2];
  const float* b1  = (const float*)d_in[3];
  const float* g1  = (const float*)d_in[4];
  const float* be1 = (const float*)d_in[5];
  const float* W2  = (const float*)d_in[6];
  const float* b2  = (const float*)d_in[7];
  const float* g2  = (const float*)d_in[8];
  const float* be2 = (const float*)d_in[9];
  const float* W3  = (const float*)d_in[10];
  const float* b3  = (const float*)d_in[11];
  float* out = (float*)d_out;

  // workspace layout (floats), ~43.4 MB total; everything fully overwritten
  // before read -> no memset needed.
  float* ws      = (float*)d_ws;
  float* h1slab  = ws;                                   // 5 * 256*2048
  float* h2slab  = h1slab + (size_t)5 * NB * NH1;        // 4 * 256*1024
  float* h1      = h2slab + (size_t)4 * NB * NH2;        // 256*2048
  float* h2      = h1     + (size_t)NB * NH1;            // 256*1024
  float* denom   = h2     + (size_t)NB * NH2;            // 256*25000

  // layer 1: x @ W1 (split-bf16, K=5000 in 5 slabs of 1000)
  gemm_split<128><<<dim3(NH1 / 128, NB / 64, 5), 256, 0, stream>>>(
      x, W1, h1slab, NB, NH1, DIN, 1000);
  ln_gelu_sum<<<NB, 256, 0, stream>>>(h1slab, 5, b1, g1, be1, h1, NH1);

  // layer 2: h1 @ W2 (split-bf16, K=2048 in 4 slabs of 512)
  gemm_split<128><<<dim3(NH2 / 128, NB / 64, 4), 256, 0, stream>>>(
      h1, W2, h2slab, NB, NH2, NH1, 512);
  ln_gelu_sum<<<NB, 256, 0, stream>>>(h2slab, 4, b2, g2, be2, h2, NH2);

  // layer 3: h2 @ W3 + b3 -> exp -> E (=d_out)
  gemm3_exp<80><<<NISO / 80, 512, 0, stream>>>(h2, W3, b3, out);

  // per-row per-gene denominators via LDS atomics
  denom_halves<<<NB, 512, 0, stream>>>(out, idx, denom);

  // grouped-softmax normalization, in place on d_out
  div_kernel<<<(NB * NISO / 4) / 256, 256, 0, stream>>>(out, denom, idx);
}